// Round 1
// baseline (61149.261 us; speedup 1.0000x reference)
//
#include <hip/hip_runtime.h>
#include <hip/hip_bf16.h>
#include <hip/hip_cooperative_groups.h>

namespace cg = cooperative_groups;

typedef __bf16 bf16;
typedef __bf16 bf16x8 __attribute__((ext_vector_type(8)));
typedef float  floatx4 __attribute__((ext_vector_type(4)));

#define NB   64      // batch
#define NT   240     // timesteps
#define NDIM 512     // audio feature dim
#define NU   1024    // LSTM units
#define NOUT 75      // motion dim
#define YC   608     // ycat padded width: 75 (y) + 512 (_h) + 21 pad
#define NWG  64
#define NTHR 1024

struct Params {
  const float* curr;      // [64,75]
  const float* bias[8];   // enc1,enc2,enc3,fc,dec1,dec2,dec3,out
  const bf16*  pk[8];     // packed weights (B-fragment layout)
  const bf16*  audio_bf;  // [64, 240*512] bf16
  bf16* h0[6];            // h double-buffer A (enc1..3, dec1..3)
  bf16* h1[6];            // h double-buffer B
  bf16* ycat;             // [64, 608]
  float* out;             // [64,240,75]
};

__device__ __forceinline__ float sigmoidf_(float x) { return 1.f / (1.f + __expf(-x)); }

// One LSTM cell stage. z[64,4096] = [seg0|seg1] @ packed([Wx;Wh]) ; gates -> h,c.
// WG w owns units [16w,16w+16). 16 waves: g = wid&3 (gate), s = wid>>2 (K-split).
// Wave (g,s) computes all 64 rows x 16 cols (cols n0=16w+1024g) over k-blocks kb = s, s+4, ...
template<int ST0, int LEN0, int KTOT>
__device__ void lstm_cell(const bf16* __restrict__ s0, const bf16* __restrict__ s1,
                          const bf16* __restrict__ pack, const float* __restrict__ bias,
                          bf16* __restrict__ hout, float (* __restrict__ cc)[16],
                          float (* __restrict__ zbuf)[64][16],
                          int w, int tid)
{
  const int lane = tid & 63, wid = tid >> 6;
  const int g = wid & 3, s = wid >> 2;
  const int lr = lane & 15, lq = lane >> 4;
  const int n0 = 16 * w + 1024 * g;
  floatx4 c0 = {0.f,0.f,0.f,0.f}, c1 = {0.f,0.f,0.f,0.f};
  floatx4 c2 = {0.f,0.f,0.f,0.f}, c3 = {0.f,0.f,0.f,0.f};
  constexpr int NKB = KTOT / 32;
  for (int kb = s; kb < NKB; kb += 4) {
    const int kq = kb * 32 + lq * 8;                        // lane's k-chunk start
    bf16x8 bfr = *(const bf16x8*)(pack + ((size_t)(kq >> 3) * 4096 + (n0 + lr)) * 8);
    const bf16* ap;
    int st;
    if (kb * 32 < LEN0) { ap = s0 + lr * ST0 + kq; st = ST0; }
    else                { ap = s1 + lr * NU + (kq - LEN0); st = NU; }
    bf16x8 x0 = *(const bf16x8*)(ap);
    bf16x8 x1 = *(const bf16x8*)(ap + 16 * st);
    bf16x8 x2 = *(const bf16x8*)(ap + 32 * st);
    bf16x8 x3 = *(const bf16x8*)(ap + 48 * st);
    c0 = __builtin_amdgcn_mfma_f32_16x16x32_bf16(x0, bfr, c0, 0, 0, 0);
    c1 = __builtin_amdgcn_mfma_f32_16x16x32_bf16(x1, bfr, c1, 0, 0, 0);
    c2 = __builtin_amdgcn_mfma_f32_16x16x32_bf16(x2, bfr, c2, 0, 0, 0);
    c3 = __builtin_amdgcn_mfma_f32_16x16x32_bf16(x3, bfr, c3, 0, 0, 0);
  }
  // spill partials: zbuf[s*4+g][row][col]; C/D layout: col = lane&15, row = lq*4+reg (+16*rowblock)
  const int slot = s * 4 + g;
  #pragma unroll
  for (int r = 0; r < 4; ++r) {
    zbuf[slot][     lq * 4 + r][lr] = c0[r];
    zbuf[slot][16 + lq * 4 + r][lr] = c1[r];
    zbuf[slot][32 + lq * 4 + r][lr] = c2[r];
    zbuf[slot][48 + lq * 4 + r][lr] = c3[r];
  }
  __syncthreads();
  // pointwise: 1024 threads = 64 rows x 16 units
  {
    const int m = tid >> 4, u = tid & 15;
    float zi = 0.f, zf = 0.f, zg = 0.f, zo = 0.f;
    #pragma unroll
    for (int ss = 0; ss < 4; ++ss) {
      zi += zbuf[ss * 4 + 0][m][u];
      zf += zbuf[ss * 4 + 1][m][u];
      zg += zbuf[ss * 4 + 2][m][u];
      zo += zbuf[ss * 4 + 3][m][u];
    }
    const int uc = 16 * w + u;
    zi += bias[uc]; zf += bias[NU + uc]; zg += bias[2 * NU + uc]; zo += bias[3 * NU + uc];
    const float cold = cc[m][u];
    const float cn = sigmoidf_(zf) * cold + sigmoidf_(zi) * tanhf(zg);
    cc[m][u] = cn;
    const float hn = sigmoidf_(zo) * tanhf(cn);
    hout[m * NU + uc] = (bf16)hn;
  }
}

// Small GEMM (fc / out): z[64,NEFF] = A[64,KTOT] @ pack. Active WGs: w < NEFF/16.
// 16 waves: v = wid&3 (row block), s = wid>>2 (K-split). Partials land in zbuf[0..3].
template<int KTOT, int NEFF>
__device__ void gemm_small(const bf16* __restrict__ a, const bf16* __restrict__ pack,
                           float (* __restrict__ zbuf)[64][16], int w, int tid)
{
  const int lane = tid & 63, wid = tid >> 6;
  const int v = wid & 3, s = wid >> 2;
  const int lr = lane & 15, lq = lane >> 4;
  const int n0 = 16 * w;
  floatx4 c = {0.f,0.f,0.f,0.f};
  constexpr int NKB = KTOT / 32;
  for (int kb = s; kb < NKB; kb += 4) {
    const int kq = kb * 32 + lq * 8;
    bf16x8 bfr = *(const bf16x8*)(pack + ((size_t)(kq >> 3) * NEFF + (n0 + lr)) * 8);
    bf16x8 x   = *(const bf16x8*)(a + (16 * v + lr) * NU + kq);
    c = __builtin_amdgcn_mfma_f32_16x16x32_bf16(x, bfr, c, 0, 0, 0);
  }
  #pragma unroll
  for (int r = 0; r < 4; ++r) zbuf[s][16 * v + lq * 4 + r][lr] = c[r];
  __syncthreads();
}

extern "C" __global__ void __launch_bounds__(NTHR)
dancer_main(Params p)
{
  __shared__ float zbuf[16][64][16];  // 64 KB: gate/K-split partial exchange
  __shared__ float cst[6][64][16];    // 24 KB: persistent c state (this WG's 16 units x 6 cells)
  cg::grid_group grid = cg::this_grid();
  const int tid = threadIdx.x;
  const int w = blockIdx.x;
  const int gtid = w * NTHR + tid;

  // ---- init: zero h buffers (both phases), build ycat, zero c ----
  for (int i = gtid; i < 6 * NB * NU; i += NWG * NTHR) {
    const int b = i >> 16, off = i & 65535;
    p.h0[b][off] = (bf16)0.f;
    p.h1[b][off] = (bf16)0.f;
  }
  for (int i = gtid; i < NB * YC; i += NWG * NTHR) {
    const int m = i / YC, c = i - m * YC;
    p.ycat[i] = (c < NOUT) ? (bf16)p.curr[m * NOUT + c] : (bf16)0.f;
  }
  for (int i = tid; i < 6 * 64 * 16; i += NTHR) (&cst[0][0][0])[i] = 0.f;
  __syncthreads();
  grid.sync();

  bf16* hA[6];  // "previous step" h (read-only this step)
  bf16* hB[6];  // "current step" h (written this step)
  #pragma unroll
  for (int c = 0; c < 6; ++c) { hA[c] = p.h0[c]; hB[c] = p.h1[c]; }

  for (int t = 0; t < NT; ++t) {
    // enc1: A = [audio_t (512) | h_enc1 (1024)]
    lstm_cell<NT * NDIM, NDIM, NDIM + NU>(p.audio_bf + t * NDIM, hA[0], p.pk[0], p.bias[0],
                                          hB[0], cst[0], zbuf, w, tid);
    grid.sync();
    lstm_cell<NU, NU, 2 * NU>(hB[0], hA[1], p.pk[1], p.bias[1], hB[1], cst[1], zbuf, w, tid);
    grid.sync();
    lstm_cell<NU, NU, 2 * NU>(hB[1], hA[2], p.pk[2], p.bias[2], hB[2], cst[2], zbuf, w, tid);
    grid.sync();
    // fc: _h = tanh(h_enc3 @ fc_W + fc_b) -> ycat cols [75,587)
    if (w < 32) {
      gemm_small<NU, 512>(hB[2], p.pk[3], zbuf, w, tid);
      const int m = tid >> 4, u = tid & 15;
      const float z = zbuf[0][m][u] + zbuf[1][m][u] + zbuf[2][m][u] + zbuf[3][m][u]
                      + p.bias[3][16 * w + u];
      p.ycat[m * YC + NOUT + 16 * w + u] = (bf16)tanhf(z);
    }
    grid.sync();
    // dec1: A = [ycat (608, = y|_h|pad) | h_dec1 (1024)]
    lstm_cell<YC, YC, YC + NU>(p.ycat, hA[3], p.pk[4], p.bias[4], hB[3], cst[3], zbuf, w, tid);
    grid.sync();
    lstm_cell<NU, NU, 2 * NU>(hB[3], hA[4], p.pk[5], p.bias[5], hB[4], cst[4], zbuf, w, tid);
    grid.sync();
    lstm_cell<NU, NU, 2 * NU>(hB[4], hA[5], p.pk[6], p.bias[6], hB[5], cst[5], zbuf, w, tid);
    grid.sync();
    // out: y = elu(h_dec3 @ out_W + out_b) -> d_out and ycat cols [0,75)
    if (w < 5) {
      gemm_small<NU, 80>(hB[5], p.pk[7], zbuf, w, tid);
      const int m = tid >> 4, u = tid & 15;
      const int n = 16 * w + u;
      if (n < NOUT) {
        const float z = zbuf[0][m][u] + zbuf[1][m][u] + zbuf[2][m][u] + zbuf[3][m][u]
                        + p.bias[7][n];
        const float y = (z > 0.f) ? z : (__expf(z) - 1.f);
        p.out[(m * NT + t) * NOUT + n] = y;
        p.ycat[m * YC + n] = (bf16)y;
      }
    }
    grid.sync();
    #pragma unroll
    for (int c = 0; c < 6; ++c) { bf16* tmp = hA[c]; hA[c] = hB[c]; hB[c] = tmp; }
  }
}

// ---- pre-kernels ----

// Pack [Wx ; zero-pad ; Wh] (fp32, row-major [K,N]) into bf16 B-fragment layout:
// dst[((k>>3)*Neff + n)*8 + (k&7)]. Reads coalesced over n, writes 16B/thread.
__global__ void pack_w(const float* __restrict__ Wx, const float* __restrict__ Wh,
                       int Kx, int KhStart, int Keff, int N, int Neff,
                       bf16* __restrict__ dst)
{
  const int idx = blockIdx.x * blockDim.x + threadIdx.x;
  const int nkb = Keff >> 3;
  const int total = nkb * Neff;
  if (idx >= total) return;
  const int kb = idx / Neff;
  const int n  = idx - kb * Neff;
  bf16x8 o;
  #pragma unroll
  for (int j = 0; j < 8; ++j) {
    const int k = kb * 8 + j;
    float v = 0.f;
    if (n < N) {
      if (k < Kx) v = Wx[(size_t)k * N + n];
      else if (k >= KhStart) v = Wh[(size_t)(k - KhStart) * N + n];
    }
    o[j] = (bf16)v;
  }
  *(bf16x8*)(dst + ((size_t)kb * Neff + n) * 8) = o;
}

__global__ void cvt_bf16(const float* __restrict__ src, bf16* __restrict__ dst, int n)
{
  const int i = blockIdx.x * blockDim.x + threadIdx.x;
  if (i < n) dst[i] = (bf16)src[i];
}

extern "C" void kernel_launch(void* const* d_in, const int* in_sizes, int n_in,
                              void* d_out, int out_size, void* d_ws, size_t ws_size,
                              hipStream_t stream)
{
  (void)in_sizes; (void)n_in; (void)out_size; (void)ws_size;

  const float* audio = (const float*)d_in[0];
  const float* curr  = (const float*)d_in[1];
  const float* Wp[8][2] = {
    { (const float*)d_in[2],  (const float*)d_in[3]  },  // enc1
    { (const float*)d_in[5],  (const float*)d_in[6]  },  // enc2
    { (const float*)d_in[8],  (const float*)d_in[9]  },  // enc3
    { (const float*)d_in[11], nullptr                },  // fc
    { (const float*)d_in[13], (const float*)d_in[14] },  // dec1
    { (const float*)d_in[16], (const float*)d_in[17] },  // dec2
    { (const float*)d_in[19], (const float*)d_in[20] },  // dec3
    { (const float*)d_in[22], nullptr                },  // out
  };
  const float* bias[8] = {
    (const float*)d_in[4],  (const float*)d_in[7],  (const float*)d_in[10],
    (const float*)d_in[12], (const float*)d_in[15], (const float*)d_in[18],
    (const float*)d_in[21], (const float*)d_in[23],
  };

  // {Kx, KhStart, Keff, N, Neff}
  const int geo[8][5] = {
    { 512,  512,  1536, 4096, 4096 },  // enc1
    { 1024, 1024, 2048, 4096, 4096 },  // enc2
    { 1024, 1024, 2048, 4096, 4096 },  // enc3
    { 1024, 1024, 1024, 512,  512  },  // fc (no Wh)
    { 587,  608,  1632, 4096, 4096 },  // dec1 (21 zero-pad rows)
    { 1024, 1024, 2048, 4096, 4096 },  // dec2
    { 1024, 1024, 2048, 4096, 4096 },  // dec3
    { 1024, 1024, 1024, 75,   80   },  // out (cols padded to 80)
  };

  char* ws = (char*)d_ws;
  size_t off = 0;
  auto take = [&](size_t bytes) -> char* {
    char* p = ws + off;
    off = (off + bytes + 255) & ~(size_t)255;
    return p;
  };

  bf16* audio_bf = (bf16*)take((size_t)NB * NT * NDIM * 2);
  bf16* pk[8];
  for (int i = 0; i < 8; ++i) pk[i] = (bf16*)take((size_t)geo[i][2] * geo[i][4] * 2);
  bf16* h0[6]; bf16* h1[6];
  for (int i = 0; i < 6; ++i) h0[i] = (bf16*)take((size_t)NB * NU * 2);
  for (int i = 0; i < 6; ++i) h1[i] = (bf16*)take((size_t)NB * NU * 2);
  bf16* ycat = (bf16*)take((size_t)NB * YC * 2);

  {
    const int n = NB * NT * NDIM;
    cvt_bf16<<<(n + 255) / 256, 256, 0, stream>>>(audio, audio_bf, n);
  }
  for (int i = 0; i < 8; ++i) {
    const int total = (geo[i][2] >> 3) * geo[i][4];
    pack_w<<<(total + 255) / 256, 256, 0, stream>>>(
        Wp[i][0], Wp[i][1], geo[i][0], geo[i][1], geo[i][2], geo[i][3], geo[i][4], pk[i]);
  }

  Params P;
  P.curr = curr;
  for (int i = 0; i < 8; ++i) { P.bias[i] = bias[i]; P.pk[i] = pk[i]; }
  P.audio_bf = audio_bf;
  for (int i = 0; i < 6; ++i) { P.h0[i] = h0[i]; P.h1[i] = h1[i]; }
  P.ycat = ycat;
  P.out = (float*)d_out;

  void* args[] = { &P };
  (void)hipLaunchCooperativeKernel(reinterpret_cast<void*>(dancer_main),
                                   dim3(NWG), dim3(NTHR), args, 0, stream);
}

// Round 2
// 50527.887 us; speedup vs baseline: 1.2102x; 1.2102x over previous
//
#include <hip/hip_runtime.h>
#include <hip/hip_bf16.h>
#include <hip/hip_cooperative_groups.h>

namespace cg = cooperative_groups;

typedef __bf16 bf16;
typedef __bf16 bf16x8 __attribute__((ext_vector_type(8)));
typedef float  floatx4 __attribute__((ext_vector_type(4)));
typedef unsigned int uint32;

#define NB   64      // batch
#define NT   240     // timesteps
#define NDIM 512     // audio feature dim
#define NU   1024    // LSTM units
#define NOUT 75      // motion dim
#define NWG  64
#define NTHR 1024

// ring slot strides (elements)
#define HSLOT (64 * 1024)
#define YW    80
#define YSLOT (64 * YW)
#define BW    528
#define BSLOT (64 * BW)

struct Params {
  const float* curr;      // [64,75]
  const float* bias[8];   // enc1,enc2,enc3,fc,dec1,dec2,dec3,out
  const bf16*  pk[8];     // packed weights (B-fragment layout)
  const bf16*  audio_bf;  // [64, 240*512] bf16
  bf16* hr[6];            // h rings [R][64][1024] (enc1..3, dec1..3)
  bf16* ybuf;             // [R][64][80]  (y feedback, cols 75..79 zero)
  bf16* hbot;             // [R][64][528] (_h bottleneck, cols 512..527 junk*0-weight)
  uint32* arrv;           // [64*32] arrival flags (128B spaced)
  uint32* gof;            // go flag
  float* out;             // [64,240,75]
  int rmask;              // ring depth - 1
  int pmask;              // heavy-sync period - 1
};

__device__ __forceinline__ float sigmoidf_(float x) { return 1.f / (1.f + __expf(-x)); }

// ---- cache-friendly grid barrier (no L2 invalidation) ----
// Caller's global stores are made visible (vmcnt drain) before arrival.
__device__ __forceinline__ void gbar(uint32* arrv, uint32* gof, uint32 sc, int w, int tid)
{
  asm volatile("s_waitcnt vmcnt(0)" ::: "memory");
  __syncthreads();
  if (w == 0) {
    if (tid == 0)
      __hip_atomic_store(&arrv[0], sc, __ATOMIC_RELAXED, __HIP_MEMORY_SCOPE_AGENT);
    if (tid < NWG) {
      int spin = 0;
      while (__hip_atomic_load(&arrv[tid * 32], __ATOMIC_RELAXED, __HIP_MEMORY_SCOPE_AGENT) < sc) {
        __builtin_amdgcn_s_sleep(1);
        if (++spin > (1 << 27)) break;  // bail instead of hard hang
      }
    }
    __syncthreads();
    if (tid == 0)
      __hip_atomic_store(gof, sc, __ATOMIC_RELAXED, __HIP_MEMORY_SCOPE_AGENT);
  } else {
    if (tid == 0) {
      __hip_atomic_store(&arrv[w * 32], sc, __ATOMIC_RELAXED, __HIP_MEMORY_SCOPE_AGENT);
      int spin = 0;
      while (__hip_atomic_load(gof, __ATOMIC_RELAXED, __HIP_MEMORY_SCOPE_AGENT) < sc) {
        __builtin_amdgcn_s_sleep(1);
        if (++spin > (1 << 27)) break;
      }
    }
    __syncthreads();
  }
}

// One LSTM cell stage. A = [p0 (B1) | p1 (B2-B1) | p2 (KTOT-B2)], all widths mult of 8.
// WG w owns units [16w,16w+16). 16 waves: g=wid&3 (gate), s=wid>>2 (K-split).
// h result staged in LDS, then written to ring slot via agent-scope dword stores.
template<int ST0, int B1, int ST1, int B2, int ST2, int KTOT>
__device__ void lstm_cell(const bf16* __restrict__ p0, const bf16* __restrict__ p1,
                          const bf16* __restrict__ p2,
                          const bf16* __restrict__ pack, const float* __restrict__ bias,
                          bf16* __restrict__ hout, float (* __restrict__ cc)[16],
                          float (* __restrict__ zbuf)[64][16], bf16 (* __restrict__ hstage)[16],
                          int w, int tid)
{
  const int lane = tid & 63, wid = tid >> 6;
  const int g = wid & 3, s = wid >> 2;
  const int lr = lane & 15, lq = lane >> 4;
  const int n0 = 16 * w + 1024 * g;
  floatx4 c0 = {0.f,0.f,0.f,0.f}, c1 = {0.f,0.f,0.f,0.f};
  floatx4 c2 = {0.f,0.f,0.f,0.f}, c3 = {0.f,0.f,0.f,0.f};
  constexpr int NKB = KTOT / 32;
  for (int kb = s; kb < NKB; kb += 4) {
    const int kq = kb * 32 + lq * 8;
    bf16x8 bfr = *(const bf16x8*)(pack + ((size_t)(kq >> 3) * 4096 + (n0 + lr)) * 8);
    const bf16* ap;
    int st;
    if (kq < B1)      { ap = p0 + lr * ST0 + kq;        st = ST0; }
    else if (kq < B2) { ap = p1 + lr * ST1 + (kq - B1); st = ST1; }
    else              { ap = p2 + lr * ST2 + (kq - B2); st = ST2; }
    bf16x8 x0 = *(const bf16x8*)(ap);
    bf16x8 x1 = *(const bf16x8*)(ap + 16 * st);
    bf16x8 x2 = *(const bf16x8*)(ap + 32 * st);
    bf16x8 x3 = *(const bf16x8*)(ap + 48 * st);
    c0 = __builtin_amdgcn_mfma_f32_16x16x32_bf16(x0, bfr, c0, 0, 0, 0);
    c1 = __builtin_amdgcn_mfma_f32_16x16x32_bf16(x1, bfr, c1, 0, 0, 0);
    c2 = __builtin_amdgcn_mfma_f32_16x16x32_bf16(x2, bfr, c2, 0, 0, 0);
    c3 = __builtin_amdgcn_mfma_f32_16x16x32_bf16(x3, bfr, c3, 0, 0, 0);
  }
  const int slot = s * 4 + g;
  #pragma unroll
  for (int r = 0; r < 4; ++r) {
    zbuf[slot][     lq * 4 + r][lr] = c0[r];
    zbuf[slot][16 + lq * 4 + r][lr] = c1[r];
    zbuf[slot][32 + lq * 4 + r][lr] = c2[r];
    zbuf[slot][48 + lq * 4 + r][lr] = c3[r];
  }
  __syncthreads();
  // pointwise: 1024 threads = 64 rows x 16 units -> hstage (LDS)
  {
    const int m = tid >> 4, u = tid & 15;
    float zi = 0.f, zf = 0.f, zg = 0.f, zo = 0.f;
    #pragma unroll
    for (int ss = 0; ss < 4; ++ss) {
      zi += zbuf[ss * 4 + 0][m][u];
      zf += zbuf[ss * 4 + 1][m][u];
      zg += zbuf[ss * 4 + 2][m][u];
      zo += zbuf[ss * 4 + 3][m][u];
    }
    const int uc = 16 * w + u;
    zi += bias[uc]; zf += bias[NU + uc]; zg += bias[2 * NU + uc]; zo += bias[3 * NU + uc];
    const float cold = cc[m][u];
    const float cn = sigmoidf_(zf) * cold + sigmoidf_(zi) * tanhf(zg);
    cc[m][u] = cn;
    hstage[m][u] = (bf16)(sigmoidf_(zo) * tanhf(cn));
  }
  __syncthreads();
  // agent-scope (write-through) dword stores so other XCDs see fresh data
  if (tid < 512) {
    const int m = tid >> 3, up = tid & 7;
    const uint32 v = *(const uint32*)&hstage[m][2 * up];
    __hip_atomic_store((uint32*)(hout + (size_t)m * NU + 16 * w) + up, v,
                       __ATOMIC_RELAXED, __HIP_MEMORY_SCOPE_AGENT);
  }
}

// Small GEMM (fc / out): z[64,NEFF] = A[64,1024] @ pack. 16 waves: v=wid&3 rows, s=wid>>2 K.
template<int NEFF>
__device__ void gemm_small(const bf16* __restrict__ a, const bf16* __restrict__ pack,
                           float (* __restrict__ zbuf)[64][16], int w, int tid)
{
  const int lane = tid & 63, wid = tid >> 6;
  const int v = wid & 3, s = wid >> 2;
  const int lr = lane & 15, lq = lane >> 4;
  const int n0 = 16 * w;
  floatx4 c = {0.f,0.f,0.f,0.f};
  for (int kb = s; kb < 32; kb += 4) {
    const int kq = kb * 32 + lq * 8;
    bf16x8 bfr = *(const bf16x8*)(pack + ((size_t)(kq >> 3) * NEFF + (n0 + lr)) * 8);
    bf16x8 x   = *(const bf16x8*)(a + (16 * v + lr) * NU + kq);
    c = __builtin_amdgcn_mfma_f32_16x16x32_bf16(x, bfr, c, 0, 0, 0);
  }
  #pragma unroll
  for (int r = 0; r < 4; ++r) zbuf[s][16 * v + lq * 4 + r][lr] = c[r];
  __syncthreads();
}

extern "C" __global__ void __launch_bounds__(NTHR)
dancer_main(Params p)
{
  __shared__ float zbuf[16][64][16];  // 64 KB partial exchange
  __shared__ float cst[6][64][16];    // 24 KB persistent c state
  __shared__ bf16  hstage[64][16];    // 2 KB h staging
  cg::grid_group grid = cg::this_grid();
  const int tid = threadIdx.x;
  const int w = blockIdx.x;
  const int gtid = w * NTHR + tid;
  const int rmask = p.rmask, pmask = p.pmask;

  // ---- init: zero flags, zero h ring slot 'rmask', ybuf slot 0 from curr, zero c ----
  if (tid == 0) {
    p.arrv[w * 32] = 0;
    if (w == 0) *p.gof = 0;
  }
  for (int i = gtid; i < 6 * NB * NU; i += NWG * NTHR) {
    const int b = i >> 16, off = i & 65535;
    p.hr[b][(size_t)rmask * HSLOT + off] = (bf16)0.f;
  }
  for (int i = gtid; i < NB * YW; i += NWG * NTHR) {
    const int m = i / YW, c = i - m * YW;
    p.ybuf[i] = (c < NOUT) ? (bf16)p.curr[m * NOUT + c] : (bf16)0.f;
  }
  for (int i = tid; i < 6 * 64 * 16; i += NTHR) (&cst[0][0][0])[i] = 0.f;
  __syncthreads();
  grid.sync();   // full fence once: init writes visible everywhere

  uint32 sc = 1;
  for (int t = 0; t < NT; ++t) {
    const int st_ = t & rmask;
    const int sp_ = (t - 1) & rmask;
    __syncthreads();  // protect zbuf/hstage reuse against previous stage's readers

    // enc1: A = [audio_t (512) | h_enc1(t-1) (1024)]
    lstm_cell<NT * NDIM, NDIM, NU, NDIM, NU, NDIM + NU>(
        p.audio_bf + t * NDIM, p.hr[0] + (size_t)sp_ * HSLOT, p.hr[0] + (size_t)sp_ * HSLOT,
        p.pk[0], p.bias[0], p.hr[0] + (size_t)st_ * HSLOT, cst[0], zbuf, &hstage[0], w, tid);
    gbar(p.arrv, p.gof, sc++, w, tid);

    lstm_cell<NU, NU, NU, NU, NU, 2 * NU>(
        p.hr[0] + (size_t)st_ * HSLOT, p.hr[1] + (size_t)sp_ * HSLOT, p.hr[1] + (size_t)sp_ * HSLOT,
        p.pk[1], p.bias[1], p.hr[1] + (size_t)st_ * HSLOT, cst[1], zbuf, &hstage[0], w, tid);
    gbar(p.arrv, p.gof, sc++, w, tid);

    lstm_cell<NU, NU, NU, NU, NU, 2 * NU>(
        p.hr[1] + (size_t)st_ * HSLOT, p.hr[2] + (size_t)sp_ * HSLOT, p.hr[2] + (size_t)sp_ * HSLOT,
        p.pk[2], p.bias[2], p.hr[2] + (size_t)st_ * HSLOT, cst[2], zbuf, &hstage[0], w, tid);
    gbar(p.arrv, p.gof, sc++, w, tid);

    // fc: _h = tanh(h_enc3 @ fc_W + b) -> hbot slot t
    if (w < 32) {
      gemm_small<512>(p.hr[2] + (size_t)st_ * HSLOT, p.pk[3], zbuf, w, tid);
      const int m = tid >> 4, u = tid & 15;
      const float z = zbuf[0][m][u] + zbuf[1][m][u] + zbuf[2][m][u] + zbuf[3][m][u]
                      + p.bias[3][16 * w + u];
      hstage[m][u] = (bf16)tanhf(z);
      __syncthreads();
      if (tid < 512) {
        const int m2 = tid >> 3, up = tid & 7;
        const uint32 v = *(const uint32*)&hstage[m2][2 * up];
        __hip_atomic_store((uint32*)(p.hbot + (size_t)st_ * BSLOT + (size_t)m2 * BW + 16 * w) + up,
                           v, __ATOMIC_RELAXED, __HIP_MEMORY_SCOPE_AGENT);
      }
    }
    gbar(p.arrv, p.gof, sc++, w, tid);

    // dec1: A = [ybuf slot t (80) | hbot slot t (528) | h_dec1(t-1) (1024)], K=1632
    lstm_cell<YW, YW, BW, YW + BW, NU, YW + BW + NU>(
        p.ybuf + (size_t)st_ * YSLOT, p.hbot + (size_t)st_ * BSLOT, p.hr[3] + (size_t)sp_ * HSLOT,
        p.pk[4], p.bias[4], p.hr[3] + (size_t)st_ * HSLOT, cst[3], zbuf, &hstage[0], w, tid);
    gbar(p.arrv, p.gof, sc++, w, tid);

    lstm_cell<NU, NU, NU, NU, NU, 2 * NU>(
        p.hr[3] + (size_t)st_ * HSLOT, p.hr[4] + (size_t)sp_ * HSLOT, p.hr[4] + (size_t)sp_ * HSLOT,
        p.pk[5], p.bias[5], p.hr[4] + (size_t)st_ * HSLOT, cst[4], zbuf, &hstage[0], w, tid);
    gbar(p.arrv, p.gof, sc++, w, tid);

    lstm_cell<NU, NU, NU, NU, NU, 2 * NU>(
        p.hr[4] + (size_t)st_ * HSLOT, p.hr[5] + (size_t)sp_ * HSLOT, p.hr[5] + (size_t)sp_ * HSLOT,
        p.pk[6], p.bias[6], p.hr[5] + (size_t)st_ * HSLOT, cst[5], zbuf, &hstage[0], w, tid);
    gbar(p.arrv, p.gof, sc++, w, tid);

    // out: y = elu(h_dec3 @ out_W + b) -> d_out and ybuf slot t+1 (no barrier:
    // covered by next step's chain before dec1 reads it)
    if (w < 5) {
      gemm_small<80>(p.hr[5] + (size_t)st_ * HSLOT, p.pk[7], zbuf, w, tid);
      const int m = tid >> 4, u = tid & 15;
      const int n = 16 * w + u;
      float y = 0.f;
      if (n < NOUT) {
        const float z = zbuf[0][m][u] + zbuf[1][m][u] + zbuf[2][m][u] + zbuf[3][m][u]
                        + p.bias[7][n];
        y = (z > 0.f) ? z : (__expf(z) - 1.f);
        p.out[(m * NT + t) * NOUT + n] = y;
      }
      hstage[m][u] = (bf16)y;
      __syncthreads();
      if (tid < 512) {
        const int m2 = tid >> 3, up = tid & 7;
        const uint32 v = *(const uint32*)&hstage[m2][2 * up];
        const size_t sn = (size_t)((t + 1) & rmask) * YSLOT;
        __hip_atomic_store((uint32*)(p.ybuf + sn + (size_t)m2 * YW + 16 * w) + up,
                           v, __ATOMIC_RELAXED, __HIP_MEMORY_SCOPE_AGENT);
      }
    }
    // periodic full sync: flush any cached ring lines before slot reuse
    if ((t & pmask) == pmask) grid.sync();
  }
}

// ---- pre-kernels ----

__global__ void pack_w(const float* __restrict__ Wx, const float* __restrict__ Wh,
                       int Kx, int KhStart, int Keff, int N, int Neff,
                       bf16* __restrict__ dst)
{
  const int idx = blockIdx.x * blockDim.x + threadIdx.x;
  const int nkb = Keff >> 3;
  const int total = nkb * Neff;
  if (idx >= total) return;
  const int kb = idx / Neff;
  const int n  = idx - kb * Neff;
  bf16x8 o;
  #pragma unroll
  for (int j = 0; j < 8; ++j) {
    const int k = kb * 8 + j;
    float v = 0.f;
    if (n < N) {
      if (k < Kx) v = Wx[(size_t)k * N + n];
      else if (k >= KhStart) v = Wh[(size_t)(k - KhStart) * N + n];
    }
    o[j] = (bf16)v;
  }
  *(bf16x8*)(dst + ((size_t)kb * Neff + n) * 8) = o;
}

// dec1: rows 0..74 = Wx[0..74] (y), 75..79 = 0, 80..591 = Wx[75..586] (_h),
//       592..607 = 0, 608..1631 = Wh.  K=1632, N=4096.
__global__ void pack_dec1(const float* __restrict__ Wx, const float* __restrict__ Wh,
                          bf16* __restrict__ dst)
{
  const int idx = blockIdx.x * blockDim.x + threadIdx.x;
  const int total = (1632 >> 3) * 4096;
  if (idx >= total) return;
  const int kb = idx >> 12;
  const int n  = idx & 4095;
  bf16x8 o;
  #pragma unroll
  for (int j = 0; j < 8; ++j) {
    const int k = kb * 8 + j;
    float v = 0.f;
    if (k < 75)                  v = Wx[(size_t)k * 4096 + n];
    else if (k >= 80 && k < 592) v = Wx[(size_t)(k - 5) * 4096 + n];
    else if (k >= 608)           v = Wh[(size_t)(k - 608) * 4096 + n];
    o[j] = (bf16)v;
  }
  *(bf16x8*)(dst + ((size_t)kb * 4096 + n) * 8) = o;
}

__global__ void cvt_bf16(const float* __restrict__ src, bf16* __restrict__ dst, int n)
{
  const int i = blockIdx.x * blockDim.x + threadIdx.x;
  if (i < n) dst[i] = (bf16)src[i];
}

extern "C" void kernel_launch(void* const* d_in, const int* in_sizes, int n_in,
                              void* d_out, int out_size, void* d_ws, size_t ws_size,
                              hipStream_t stream)
{
  (void)in_sizes; (void)n_in; (void)out_size;

  const float* audio = (const float*)d_in[0];
  const float* curr  = (const float*)d_in[1];
  const float* Wp[8][2] = {
    { (const float*)d_in[2],  (const float*)d_in[3]  },  // enc1
    { (const float*)d_in[5],  (const float*)d_in[6]  },  // enc2
    { (const float*)d_in[8],  (const float*)d_in[9]  },  // enc3
    { (const float*)d_in[11], nullptr                },  // fc
    { (const float*)d_in[13], (const float*)d_in[14] },  // dec1
    { (const float*)d_in[16], (const float*)d_in[17] },  // dec2
    { (const float*)d_in[19], (const float*)d_in[20] },  // dec3
    { (const float*)d_in[22], nullptr                },  // out
  };
  const float* bias[8] = {
    (const float*)d_in[4],  (const float*)d_in[7],  (const float*)d_in[10],
    (const float*)d_in[12], (const float*)d_in[15], (const float*)d_in[18],
    (const float*)d_in[21], (const float*)d_in[23],
  };

  // {Kx, KhStart, Keff, N, Neff}; dec1 handled by pack_dec1
  const int geo[8][5] = {
    { 512,  512,  1536, 4096, 4096 },  // enc1
    { 1024, 1024, 2048, 4096, 4096 },  // enc2
    { 1024, 1024, 2048, 4096, 4096 },  // enc3
    { 1024, 1024, 1024, 512,  512  },  // fc
    { 0,    0,    1632, 4096, 4096 },  // dec1 (custom)
    { 1024, 1024, 2048, 4096, 4096 },  // dec2
    { 1024, 1024, 2048, 4096, 4096 },  // dec3
    { 1024, 1024, 1024, 75,   80   },  // out
  };

  char* ws = (char*)d_ws;
  size_t off = 0;
  auto take = [&](size_t bytes) -> char* {
    char* p = ws + off;
    off = (off + bytes + 255) & ~(size_t)255;
    return p;
  };

  bf16* audio_bf = (bf16*)take((size_t)NB * NT * NDIM * 2);
  bf16* pk[8];
  for (int i = 0; i < 8; ++i) pk[i] = (bf16*)take((size_t)geo[i][2] * geo[i][4] * 2);
  uint32* arrv = (uint32*)take(64 * 32 * sizeof(uint32));
  uint32* gof  = (uint32*)take(256);

  // pick ring depth that fits ws
  const size_t slot_bytes = (size_t)6 * HSLOT * 2 + (size_t)YSLOT * 2 + (size_t)BSLOT * 2 + 4096;
  int R = 32;
  while (R > 4 && off + (size_t)R * slot_bytes + (1 << 20) > ws_size) R >>= 1;

  bf16* hr[6];
  for (int i = 0; i < 6; ++i) hr[i] = (bf16*)take((size_t)R * HSLOT * 2);
  bf16* ybuf = (bf16*)take((size_t)R * YSLOT * 2);
  bf16* hbot = (bf16*)take((size_t)R * BSLOT * 2);

  {
    const int n = NB * NT * NDIM;
    cvt_bf16<<<(n + 255) / 256, 256, 0, stream>>>(audio, audio_bf, n);
  }
  for (int i = 0; i < 8; ++i) {
    if (i == 4) {
      const int total = (1632 >> 3) * 4096;
      pack_dec1<<<(total + 255) / 256, 256, 0, stream>>>(Wp[4][0], Wp[4][1], pk[4]);
    } else {
      const int total = (geo[i][2] >> 3) * geo[i][4];
      pack_w<<<(total + 255) / 256, 256, 0, stream>>>(
          Wp[i][0], Wp[i][1], geo[i][0], geo[i][1], geo[i][2], geo[i][3], geo[i][4], pk[i]);
    }
  }

  Params P;
  P.curr = curr;
  for (int i = 0; i < 8; ++i) { P.bias[i] = bias[i]; P.pk[i] = pk[i]; }
  P.audio_bf = audio_bf;
  for (int i = 0; i < 6; ++i) P.hr[i] = hr[i];
  P.ybuf = ybuf;
  P.hbot = hbot;
  P.arrv = arrv;
  P.gof = gof;
  P.out = (float*)d_out;
  P.rmask = R - 1;
  P.pmask = (R >> 1) - 1;

  void* args[] = { &P };
  (void)hipLaunchCooperativeKernel(reinterpret_cast<void*>(dancer_main),
                                   dim3(NWG), dim3(NTHR), args, 0, stream);
}